// Round 3
// baseline (322.343 us; speedup 1.0000x reference)
//
#include <hip/hip_runtime.h>

// SelfAttention: x(8,2048,768) fp32, W_q/W_k/W_v (768,768) fp32 -> H fp32.
// Algebraic rewrite: S = x (Wq^T Wk / sqrt(D)) x^T:
//   cvt(x,Wv) ; transpose(Wq,Wk) ; G2 = NT(WkT,WqT)*scale ; T~ = NT(x,G2)
//   Vt = (x@Wv^T)^T ; P' = exp(NT(T~,x)) + rowsums ; H = NT(P',Vt)/rowsum
// GEMM core: 256x256, BK=64, 8 waves (2Mx4N), per-wave 128x64, acc[8][4].
// R3 schedule: register-pipelined phases (frag ds_reads one phase ahead,
// counted lgkmcnt, ONE barrier/phase), row-split LDS regions with the proven
// 128B-row chunk^(row&7) swizzle, counted-vmcnt staging ledger (VMW(4)/phase,
// never 0 in main loop). LDS = exactly 128 KiB = 2 buf x {Bt,Bb,At,Ab} x 16KB.
// Region r: 0=B rows n0+0..127, 1=B+128, 2=A rows m0+0..127, 3=A+128.
// Staging stream: at tile t phase p: p0->At(t+1), p1->Ab(t+1), p2->Bt(t+2), p3->Bb(t+2).

typedef _Float16 f16;
typedef __attribute__((ext_vector_type(4))) _Float16 f16x4;
typedef __attribute__((ext_vector_type(8))) _Float16 f16x8;
typedef __attribute__((ext_vector_type(4))) float    f32x4;

#define SEQ   2048
#define DIM   768
#define NBAT  8
#define MTOT  (NBAT * SEQ)          // 16384
#define XN    ((long)MTOT * DIM)    // 12582912
#define WN    (DIM * DIM)           // 589824
#define SB    ((long)SEQ * SEQ)
#define QB    ((long)SEQ * DIM)
#define XN4   3145728               // XN/4
#define WN4   147456                // WN/4

__device__ __forceinline__ void async_cp16(const void* g, void* l) {
  __builtin_amdgcn_global_load_lds((__attribute__((address_space(1))) void*)g,
                                   (__attribute__((address_space(3))) void*)l,
                                   16, 0, 0);
}

// fp32 -> f16 for x and Wv.
__global__ void cvt_all(const float* __restrict__ x, const float* __restrict__ wv,
                        f16* __restrict__ x16, f16* __restrict__ wv16) {
  int i = blockIdx.x * 256 + threadIdx.x;      // float4 index
  const float* src; f16* dst; int idx;
  if (i < XN4) { src = x; dst = x16; idx = i; }
  else { src = wv; dst = wv16; idx = i - XN4; }
  float4 v = ((const float4*)src)[idx];
  f16x4 o = {(f16)v.x, (f16)v.y, (f16)v.z, (f16)v.w};
  ((f16x4*)dst)[idx] = o;
}

// Wq,Wk fp32 -> transposed f16 (WT[d][k] = W[k][d]).
__global__ void transpose_w(const float* __restrict__ wq, const float* __restrict__ wk,
                            f16* __restrict__ wqt, f16* __restrict__ wkt) {
  __shared__ float t[32][33];
  const float* src = blockIdx.z ? wk : wq;
  f16* dst = blockIdx.z ? wkt : wqt;
  const int bx = blockIdx.x * 32, by = blockIdx.y * 32;
  const int tx = threadIdx.x & 31, ty = threadIdx.x >> 5;   // 32 x 8
#pragma unroll
  for (int r = 0; r < 4; ++r)
    t[ty + 8 * r][tx] = src[(long)(by + ty + 8 * r) * DIM + bx + tx];
  __syncthreads();
#pragma unroll
  for (int r = 0; r < 4; ++r)
    dst[(long)(bx + ty + 8 * r) * DIM + by + tx] = (f16)t[tx][ty + 8 * r];
}

// ---------------- 256x256 register-pipelined NT GEMM ----------------
// MODE 0: f16 row-major out, scaled by `scale`.
// MODE 1: f16 out = exp(acc); rowsum partials -> Rsum[z][32][2048].
// MODE 2: fp32 out = acc * (1/rowsum) from Rsum partials.
// MODE 3: f16 transposed out Vt[b][n][m-local]. SWAP=false.
// SWAP=true: mfma(bf,af): m = lane&15 side, regs = 4 consecutive n.

#define VMW(n_) asm volatile("s_waitcnt vmcnt(" #n_ ")" ::: "memory")
#define NOW ((void)0)

// stage region R_ of buffer BUF_ at k-offset K0_ (2 x global_load_lds / wave)
#define STG(BUF_, R_, K0_) do { \
    f16* d_ = smH + (BUF_) * 32768 + (R_) * 8192 + (tid << 3); \
    const f16* s_ = (((R_) < 2) ? gB : gA) + (long)(((R_) & 1) * 128) * K + (K0_); \
    async_cp16(s_, d_); \
    async_cp16(s_ + 64 * (long)K, d_ + 4096); \
  } while (0)

// read 4 A-frags (16B each) for phase (KK_, MH_) of the tile in buffer BUF_
#define RD_A(SET_, BUF_, KK_, MH_) do { \
    const f16* pA_ = smH + (BUF_) * 32768 + aB + (MH_) * 4096 + cq##KK_; \
    aR[SET_][0] = *(const f16x8*)(pA_); \
    aR[SET_][1] = *(const f16x8*)(pA_ + 1024); \
    aR[SET_][2] = *(const f16x8*)(pA_ + 2048); \
    aR[SET_][3] = *(const f16x8*)(pA_ + 3072); \
  } while (0)

#define RD_B(BUF_, KK_) do { \
    const f16* pB_ = smH + (BUF_) * 32768 + bB + cq##KK_; \
    bR[KK_][0] = *(const f16x8*)(pB_); \
    bR[KK_][1] = *(const f16x8*)(pB_ + 1024); \
    bR[KK_][2] = *(const f16x8*)(pB_ + 2048); \
    bR[KK_][3] = *(const f16x8*)(pB_ + 3072); \
  } while (0)

#define MM(SET_, KK_, MH_) do { \
    _Pragma("unroll") \
    for (int i_ = 0; i_ < 4; ++i_) \
      _Pragma("unroll") \
      for (int j_ = 0; j_ < 4; ++j_) \
        acc[(MH_) * 4 + i_][j_] = SWAP \
          ? __builtin_amdgcn_mfma_f32_16x16x32_f16(bR[KK_][j_], aR[SET_][i_], acc[(MH_) * 4 + i_][j_], 0, 0, 0) \
          : __builtin_amdgcn_mfma_f32_16x16x32_f16(aR[SET_][i_], bR[KK_][j_], acc[(MH_) * 4 + i_][j_], 0, 0, 0); \
  } while (0)

// phase: stage; counted vmcnt; ds_read frags for NEXT phase; wait prev phase's
// reads (lgkm == count issued this phase); MFMA this phase's frags; barrier.
#define PH(SET_, KK_, MH_, LGKM_, STG_, VMW_, RDS_) do { \
    STG_; \
    VMW_; \
    RDS_; \
    asm volatile("s_waitcnt lgkmcnt(" #LGKM_ ")" ::: "memory"); \
    __builtin_amdgcn_sched_barrier(0); \
    __builtin_amdgcn_s_setprio(1); \
    MM(SET_, KK_, MH_); \
    __builtin_amdgcn_s_setprio(0); \
    __builtin_amdgcn_s_barrier(); \
    __builtin_amdgcn_sched_barrier(0); \
  } while (0)

#define TILE(BUF_, T_) do { \
    PH(0, 0, 0, 4, STG((BUF_) ^ 1, 2, ((T_) + 1) * 64), VMW(4), RD_A(1, BUF_, 0, 1)); \
    PH(1, 0, 1, 8, STG((BUF_) ^ 1, 3, ((T_) + 1) * 64), VMW(4), { RD_A(0, BUF_, 1, 0); RD_B(BUF_, 1); }); \
    PH(0, 1, 0, 4, STG(BUF_, 0, ((T_) + 2) * 64), VMW(4), RD_A(1, BUF_, 1, 1)); \
    PH(1, 1, 1, 8, STG(BUF_, 1, ((T_) + 2) * 64), VMW(4), { RD_A(0, (BUF_) ^ 1, 0, 0); RD_B((BUF_) ^ 1, 0); }); \
  } while (0)

template <int MODE, bool SWAP>
__global__ __launch_bounds__(512, 2)
void gemm_nt(const f16* __restrict__ Abase, long sAz,
             const f16* __restrict__ Bbase, long sBz,
             void* __restrict__ Cbase, long sCz,
             float* __restrict__ Rsum,
             int N, int K, float scale)
{
  __shared__ __align__(16) char smem[131072];   // exactly 128 KiB; epilogue aliases
  f16* smH = (f16*)smem;

  const int tid  = threadIdx.x;
  const int z    = blockIdx.z;
  const int m0   = blockIdx.x * 256;
  const int n0   = blockIdx.y * 256;
  const int wave = tid >> 6;
  const int lane = tid & 63;
  const int wr   = wave >> 2;         // 0..1  (M half)
  const int wc   = wave & 3;          // 0..3  (N quarter)

  const f16* A = Abase + (long)z * sAz;
  const f16* B = Bbase + (long)z * sBz;

  // staging: thread covers rows srow, srow+64 of a 128-row region; chunk slot
  // tid&7; global source chunk inverse-swizzled by row&7 (invariant mod 64/128).
  const int srow = tid >> 3;
  const int co   = (((tid & 7) ^ (srow & 7))) * 8;
  const f16* gA = A + (long)(m0 + srow) * K + co;
  const f16* gB = B + (long)(n0 + srow) * K + co;

  // fragment addressing: region row = <block base> + frow; chunk (kk*4+q)^(frow&7)
  const int frow = lane & 15;
  const int q    = lane >> 4;
  const int sw   = frow & 7;
  const int cq0  = ((q) ^ sw) * 8;
  const int cq1  = ((4 + q) ^ sw) * 8;
  const int aB   = (2 + wr) * 8192 + frow * 64;
  const int bB   = (wc >> 1) * 8192 + (wc & 1) * 4096 + frow * 64;

  f32x4 acc[8][4] = {};
  f16x8 aR[2][4], bR[2][4];
  const int NT = K >> 6;              // even (12 or 32) for all call sites

  // prologue: tile0 all 4 regions, tile1 Bt,Bb; land tile0; read tile0 ph0 frags
  STG(0, 0, 0); STG(0, 1, 0); STG(0, 2, 0); STG(0, 3, 0);
  STG(1, 0, 64); STG(1, 1, 64);
  VMW(4);
  __builtin_amdgcn_s_barrier();
  __builtin_amdgcn_sched_barrier(0);
  RD_A(0, 0, 0, 0);
  RD_B(0, 0);

  int t = 0;
  for (; t + 3 < NT; t += 2) { TILE(0, t); TILE(1, t + 1); }

  // peel t = NT-2 (buf 0)
  PH(0, 0, 0, 4, STG(1, 2, (NT - 1) * 64), VMW(4), RD_A(1, 0, 0, 1));
  PH(1, 0, 1, 8, STG(1, 3, (NT - 1) * 64), VMW(4), { RD_A(0, 0, 1, 0); RD_B(0, 1); });
  PH(0, 1, 0, 4, NOW, VMW(4), RD_A(1, 0, 1, 1));
  PH(1, 1, 1, 8, NOW, VMW(0), { RD_A(0, 1, 0, 0); RD_B(1, 0); });
  // peel t = NT-1 (buf 1)
  PH(0, 0, 0, 4, NOW, NOW, RD_A(1, 1, 0, 1));
  PH(1, 0, 1, 8, NOW, NOW, { RD_A(0, 1, 1, 0); RD_B(1, 1); });
  PH(0, 1, 0, 4, NOW, NOW, RD_A(1, 1, 1, 1));
  PH(1, 1, 1, 0, NOW, NOW, NOW);

  // ---- epilogues (smem aliased; all LDS reads/writes of loop complete) ----
  const int TS = 272;   // f16 tile stride (halfs), 16B-aligned rows
  // output mapping (SWAP=true): m = wr*128 + ii*16 + frow ; n = wc*64 + j*16 + q*4 + r
  // (SWAP=false / MODE3):       n = wc*64 + j*16 + frow ; m = wr*128 + ii*16 + q*4 + r

  if constexpr (MODE == 0 || MODE == 1) {
    f16* T = (f16*)smem;   // [128][TS]
    f16* C = (f16*)Cbase + (long)z * sCz;
    const float sc = (MODE == 0) ? scale : 1.0f;
    float rs[8] = {};
#pragma unroll
    for (int p = 0; p < 2; ++p) {
      if (wr == p) {
#pragma unroll
        for (int ii = 0; ii < 8; ++ii)
#pragma unroll
          for (int j = 0; j < 4; ++j) {
            f16x4 v;
#pragma unroll
            for (int r = 0; r < 4; ++r) {
              float xv = acc[ii][j][r];
              if (MODE == 1) xv = __expf(xv); else xv *= sc;
              v[r] = (f16)xv;
              if (MODE == 1) rs[ii] += (float)v[r];   // sum of f16-rounded values
            }
            *(f16x4*)&T[(ii * 16 + frow) * TS + wc * 64 + j * 16 + q * 4] = v;
          }
      }
      __syncthreads();
      const int row = tid >> 2;
#pragma unroll
      for (int k = 0; k < 8; ++k) {
        const int ch = (tid & 3) + 4 * k;
        f16x8 v = *(const f16x8*)&T[row * TS + ch * 8];
        *(f16x8*)&C[(long)(m0 + p * 128 + row) * N + n0 + ch * 8] = v;
      }
      if (p == 0) __syncthreads();
    }
    if constexpr (MODE == 1) {
#pragma unroll
      for (int ii = 0; ii < 8; ++ii) {
        rs[ii] += __shfl_xor(rs[ii], 16);
        rs[ii] += __shfl_xor(rs[ii], 32);   // full 64-col segment sum
      }
      if (lane < 16) {   // q==0 lanes hold reduced sums; frow==lane
        float* rp = Rsum + ((long)z * 32 + blockIdx.y * 4 + wc) * SEQ + m0 + wr * 128;
#pragma unroll
        for (int ii = 0; ii < 8; ++ii) rp[ii * 16 + frow] = rs[ii];
      }
    }
  }

  if constexpr (MODE == 3) {   // Vt[b][d][s]; SWAP=false
    f16* T = (f16*)smem;       // [128 n-rows][TS] holding m(=s) contiguous
    f16* C = (f16*)Cbase;
    const int b = m0 >> 11, sl = m0 & 2047;
#pragma unroll
    for (int p = 0; p < 2; ++p) {
      if ((wc >> 1) == p) {
#pragma unroll
        for (int ii = 0; ii < 8; ++ii)
#pragma unroll
          for (int j = 0; j < 4; ++j) {
            f16x4 v = {(f16)acc[ii][j][0], (f16)acc[ii][j][1],
                       (f16)acc[ii][j][2], (f16)acc[ii][j][3]};
            *(f16x4*)&T[((wc & 1) * 64 + j * 16 + frow) * TS + wr * 128 + ii * 16 + q * 4] = v;
          }
      }
      __syncthreads();
      const int row = tid >> 2;
#pragma unroll
      for (int k = 0; k < 8; ++k) {
        const int ch = (tid & 3) + 4 * k;
        f16x8 v = *(const f16x8*)&T[row * TS + ch * 8];
        *(f16x8*)&C[(long)b * QB + (long)(n0 + p * 128 + row) * SEQ + sl + ch * 8] = v;
      }
      if (p == 0) __syncthreads();
    }
  }

  if constexpr (MODE == 2) {   // fp32 out, normalized; 4 passes of 64 rows
    // rowsum reciprocals: computed here (post-loop), aliased LDS at 100 KiB
    float* sinv = (float*)(smem + 102400);   // 1 KiB, disjoint from Tf (66 KiB)
    if (tid < 256) {
      const float* rp = Rsum + (long)z * 32 * SEQ + m0 + tid;
      float s = 0.f;
#pragma unroll
      for (int k = 0; k < 32; ++k) s += rp[k * SEQ];
      sinv[tid] = 1.0f / s;
    }
    __syncthreads();
    float inv[8];
#pragma unroll
    for (int ii = 0; ii < 8; ++ii) inv[ii] = sinv[wr * 128 + ii * 16 + frow];
    float* Tf = (float*)smem;  // [64][FS] fp32
    const int FS = 264;
    float* C = (float*)Cbase + (long)z * sCz;
#pragma unroll
    for (int p = 0; p < 4; ++p) {
      if (wr == (p >> 1)) {
        const int ib = (p & 1) * 4;
#pragma unroll
        for (int i2 = 0; i2 < 4; ++i2)
#pragma unroll
          for (int j = 0; j < 4; ++j) {
            f32x4 v = acc[ib + i2][j] * inv[ib + i2];
            *(f32x4*)&Tf[(i2 * 16 + frow) * FS + wc * 64 + j * 16 + q * 4] = v;
          }
      }
      __syncthreads();
      const int row = tid >> 3;
#pragma unroll
      for (int k = 0; k < 8; ++k) {
        const int ch = (tid & 7) + 8 * k;
        f32x4 v = *(const f32x4*)&Tf[row * FS + ch * 4];
        *(f32x4*)&C[(long)(m0 + p * 64 + row) * N + n0 + ch * 4] = v;
      }
      if (p < 3) __syncthreads();
    }
  }
}

extern "C" void kernel_launch(void* const* d_in, const int* in_sizes, int n_in,
                              void* d_out, int out_size, void* d_ws, size_t ws_size,
                              hipStream_t stream) {
  const float* x  = (const float*)d_in[0];
  const float* Wq = (const float*)d_in[1];
  const float* Wk = (const float*)d_in[2];
  const float* Wv = (const float*)d_in[3];

  f16* ws    = (f16*)d_ws;
  f16* x16   = ws;                  // XN
  f16* Wv16  = x16 + XN;            // WN
  f16* WqT16 = Wv16 + WN;           // WN
  f16* WkT16 = WqT16 + WN;          // WN
  f16* G2    = WkT16 + WN;          // WN   G2[e][d] = sum_k Wk[k][e]Wq[k][d] * scale
  f16* T16   = G2 + WN;             // XN   T~ = x @ G2^T
  f16* Vt16  = T16 + XN;            // XN   [b][d][s]
  f16* S16   = Vt16 + XN;           // NBAT*SB (exp scores, unnormalized)
  float* rsumP = (float*)(S16 + (long)NBAT * SB);   // [8][32][2048] partials

  cvt_all<<<(XN4 + WN4) / 256, 256, 0, stream>>>(x, Wv, x16, Wv16);
  transpose_w<<<dim3(24, 24, 2), 256, 0, stream>>>(Wq, Wk, WqT16, WkT16);

  dim3 blk(512);
  // G2 = NT(WkT, WqT) * 1/sqrt(768)  (768x768x768)
  gemm_nt<0, true><<<dim3(3, 3, 1), blk, 0, stream>>>(
      WkT16, 0L, WqT16, 0L, (void*)G2, 0L, nullptr, DIM, DIM, 0.03608439182435161f);
  // T~ = NT(x16, G2)  (16384x768x768)
  gemm_nt<0, true><<<dim3(MTOT / 256, DIM / 256, 1), blk, 0, stream>>>(
      x16, 0L, G2, 0L, (void*)T16, 0L, nullptr, DIM, DIM, 1.0f);
  // Vt = (x @ Wv^T)^T per batch  (16384x768x768, transposed out)
  gemm_nt<3, false><<<dim3(MTOT / 256, DIM / 256, 1), blk, 0, stream>>>(
      x16, 0L, Wv16, 0L, (void*)Vt16, 0L, nullptr, DIM, DIM, 1.0f);
  // P' = exp(T~ x^T) per batch + rowsum partials  (2048x2048x768 x8)
  gemm_nt<1, true><<<dim3(SEQ / 256, SEQ / 256, NBAT), blk, 0, stream>>>(
      T16, QB, x16, QB, (void*)S16, SB, rsumP, SEQ, DIM, 1.0f);
  // H = (P' @ Vt^T) / rowsum, fp32  (2048x768x2048 x8)
  gemm_nt<2, true><<<dim3(SEQ / 256, DIM / 256, NBAT), blk, 0, stream>>>(
      S16, SB, Vt16, QB, d_out, QB, rsumP, DIM, SEQ, 1.0f);
}